// Round 3
// baseline (1214.443 us; speedup 1.0000x reference)
//
#include <hip/hip_runtime.h>
#include <stdint.h>

typedef unsigned short u16;
typedef unsigned int u32;
typedef short bf16x8 __attribute__((ext_vector_type(8)));
typedef float f32x4 __attribute__((ext_vector_type(4)));

#define E_ 8
#define H_ 2048
#define F_ 4096
#define T_ 16384
#define TE_ 2048

#define WAITV(n) asm volatile("s_waitcnt vmcnt(" #n ")" ::: "memory")
#define BARF                              \
  do {                                    \
    asm volatile("" ::: "memory");        \
    __builtin_amdgcn_s_barrier();         \
    asm volatile("" ::: "memory");        \
  } while (0)

__device__ __forceinline__ u16 f2bf(float f) {
  u32 u = __builtin_bit_cast(u32, f);
  u32 r = (u + 0x7FFFu + ((u >> 16) & 1u)) >> 16;  // RNE
  return (u16)r;
}

__device__ __forceinline__ void gload16(const u16* g, u16* l) {
  __builtin_amdgcn_global_load_lds(
      (__attribute__((address_space(1))) void*)g,
      (__attribute__((address_space(3))) void*)l, 16, 0, 0);
}

__device__ __forceinline__ void mfma_b(f32x4& acc, bf16x8 a, bf16x8 b) {
  asm volatile("v_mfma_f32_16x16x32_bf16 %0, %1, %2, %0"
               : "+v"(acc)
               : "v"(a), "v"(b));
}

// ---------- fp32 -> bf16 convert ----------

__global__ __launch_bounds__(256) void cvt_kernel(const float* __restrict__ src,
                                                  u16* __restrict__ dst,
                                                  long n4) {
  long i = (long)blockIdx.x * blockDim.x + threadIdx.x;
  long stride = (long)gridDim.x * blockDim.x;
  const float4* s4 = (const float4*)src;
  uint2* d4 = (uint2*)dst;
  for (; i < n4; i += stride) {
    float4 v = s4[i];
    uint2 o;
    o.x = (u32)f2bf(v.x) | ((u32)f2bf(v.y) << 16);
    o.y = (u32)f2bf(v.z) | ((u32)f2bf(v.w) << 16);
    d4[i] = o;
  }
}

// ============ 8-phase 256x256 GEMM1 (fused SiLU) ============
// Block: 256 token rows x (128 gate + 128 up interleaved) cols, BK=64.
// 8 waves 2Mx4N; wave tile 128x64. LDS 128 KiB: [2 buf][A,B][2 kh][16 chunks
// x 1KiB lane-linear]. B-chunk c: isUp=c&1, pair=c>>1 (gate/up interleave).

__global__ __launch_bounds__(512, 2) void gemm1_silu(
    const u16* __restrict__ Xb, const u16* __restrict__ Wgu,
    u16* __restrict__ Hid) {
  const int nx = gridDim.x, ny = gridDim.y;
  int lin = blockIdx.x + nx * (blockIdx.y + ny * blockIdx.z);
  const int nwg = nx * ny * gridDim.z;
  int swz = (lin & 7) * (nwg >> 3) + (lin >> 3);
  const int bx = swz % nx;
  int tq = swz / nx;
  const int by = tq % ny;
  const int z = tq / ny;
  Xb += (size_t)z * TE_ * H_;
  Wgu += (size_t)z * 2 * F_ * H_;
  Hid += (size_t)z * TE_ * F_;

  const int tid = threadIdx.x, w = tid >> 6, lane = tid & 63;
  const int wr = w >> 2, wc = w & 3;
  const int r15 = lane & 15, g4 = lane >> 4;

  __shared__ __attribute__((aligned(16))) u16 lds[65536];
  // elem offset: buf*32768 + op*16384 + kh*8192 + chunk*512 + lane*8

  const u16* gA = Xb + (size_t)(by * 256 + r15) * H_ + g4 * 8;
  const u16* gB =
      Wgu + (size_t)(((w & 1) ? F_ : 0) + bx * 128 + r15) * H_ + g4 * 8;

  auto stA = [&](int t, int kh, int buf) {
#pragma unroll
    for (int i = 0; i < 2; ++i) {
      const int c = i * 8 + w;
      gload16(gA + (size_t)(c * 16) * H_ + t * 64 + kh * 32,
              lds + buf * 32768 + kh * 8192 + c * 512);
    }
  };
  auto stB = [&](int t, int kh, int buf) {
#pragma unroll
    for (int i = 0; i < 2; ++i) {
      const int c = i * 8 + w;
      gload16(gB + (size_t)((i * 4 + (w >> 1)) * 16) * H_ + t * 64 + kh * 32,
              lds + buf * 32768 + 16384 + kh * 8192 + c * 512);
    }
  };

  const u16* ldsA = lds + lane * 8;
  const u16* ldsB = lds + 16384 + lane * 8;

  f32x4 acc[8][4] = {};
  bf16x8 a[4], b[4];

  auto dsB = [&](int buf, int kh) {
#pragma unroll
    for (int ni = 0; ni < 4; ++ni)
      b[ni] =
          *(const bf16x8*)&ldsB[buf * 32768 + kh * 8192 + (wc * 4 + ni) * 512];
  };
  auto dsA = [&](int buf, int kh, int mh) {
#pragma unroll
    for (int mi = 0; mi < 4; ++mi)
      a[mi] = *(const bf16x8*)&ldsA[buf * 32768 + kh * 8192 +
                                    (wr * 8 + mh * 4 + mi) * 512];
  };
  auto mm = [&](int mh) {
    __builtin_amdgcn_s_setprio(1);
#pragma unroll
    for (int mi = 0; mi < 4; ++mi)
#pragma unroll
      for (int ni = 0; ni < 4; ++ni) mfma_b(acc[mh * 4 + mi][ni], a[mi], b[ni]);
    __builtin_amdgcn_s_setprio(0);
  };

  // prologue: tile0 all 4 halves, tile1 {Bk0, Ak0, Bk1}
  stB(0, 0, 0); stA(0, 0, 0); stB(0, 1, 0); stA(0, 1, 0);
  stB(1, 0, 1); stA(1, 0, 1); stB(1, 1, 1);
  WAITV(6);
  BARF;

  const int NT = H_ / 64;  // 32
  for (int t = 0; t <= NT - 4; t += 2) {
    dsB(0, 0); dsA(0, 0, 0); stA(t + 1, 1, 1);           BARF; mm(0); BARF;
    dsA(0, 0, 1);            stB(t + 2, 0, 0);           BARF; mm(1); BARF;
    dsB(0, 1); dsA(0, 1, 0); stA(t + 2, 0, 0);           BARF; mm(0); BARF;
    dsA(0, 1, 1);            stB(t + 2, 1, 0); WAITV(6); BARF; mm(1); BARF;
    dsB(1, 0); dsA(1, 0, 0); stA(t + 2, 1, 0);           BARF; mm(0); BARF;
    dsA(1, 0, 1);            stB(t + 3, 0, 1);           BARF; mm(1); BARF;
    dsB(1, 1); dsA(1, 1, 0); stA(t + 3, 0, 1);           BARF; mm(0); BARF;
    dsA(1, 1, 1);            stB(t + 3, 1, 1); WAITV(6); BARF; mm(1); BARF;
  }
  // peeled last iteration (tiles NT-2 / NT-1)
  dsB(0, 0); dsA(0, 0, 0); stA(NT - 1, 1, 1); BARF; mm(0); BARF;
  dsA(0, 0, 1);                               BARF; mm(1); BARF;
  dsB(0, 1); dsA(0, 1, 0);                    BARF; mm(0); BARF;
  dsA(0, 1, 1);            WAITV(0);          BARF; mm(1); BARF;
  dsB(1, 0); dsA(1, 0, 0);                    BARF; mm(0); BARF;
  dsA(1, 0, 1);                               BARF; mm(1); BARF;
  dsB(1, 1); dsA(1, 1, 0);                    BARF; mm(0); BARF;
  dsA(1, 1, 1);                               BARF; mm(1);

  // epilogue: silu(gate)*up -> bf16
  const int row0 = by * 256 + wr * 128 + g4 * 4;
  const int colb = bx * 128 + wc * 32 + r15;
#pragma unroll
  for (int mI = 0; mI < 8; ++mI)
#pragma unroll
    for (int k = 0; k < 2; ++k)
#pragma unroll
      for (int j = 0; j < 4; ++j) {
        float g = acc[mI][2 * k][j];
        float u = acc[mI][2 * k + 1][j];
        float h = (g / (1.f + __expf(-g))) * u;
        Hid[(size_t)(row0 + mI * 16 + j) * F_ + colb + k * 16] = f2bf(h);
      }
}

// ============ 8-phase 256x256 GEMM2 (fp32 out) ============

__global__ __launch_bounds__(512, 2) void gemm2_down(
    const u16* __restrict__ Hd, const u16* __restrict__ Wd,
    float* __restrict__ Out) {
  const int nx = gridDim.x, ny = gridDim.y;
  int lin = blockIdx.x + nx * (blockIdx.y + ny * blockIdx.z);
  const int nwg = nx * ny * gridDim.z;
  int swz = (lin & 7) * (nwg >> 3) + (lin >> 3);
  const int bx = swz % nx;
  int tq = swz / nx;
  const int by = tq % ny;
  const int z = tq / ny;
  Hd += (size_t)z * TE_ * F_;
  Wd += (size_t)z * H_ * F_;
  Out += (size_t)z * TE_ * H_;

  const int tid = threadIdx.x, w = tid >> 6, lane = tid & 63;
  const int wr = w >> 2, wc = w & 3;
  const int r15 = lane & 15, g4 = lane >> 4;

  __shared__ __attribute__((aligned(16))) u16 lds[65536];

  const u16* gA = Hd + (size_t)(by * 256 + r15) * F_ + g4 * 8;
  const u16* gB = Wd + (size_t)(bx * 256 + r15) * F_ + g4 * 8;

  auto stA = [&](int t, int kh, int buf) {
#pragma unroll
    for (int i = 0; i < 2; ++i) {
      const int c = i * 8 + w;
      gload16(gA + (size_t)(c * 16) * F_ + t * 64 + kh * 32,
              lds + buf * 32768 + kh * 8192 + c * 512);
    }
  };
  auto stB = [&](int t, int kh, int buf) {
#pragma unroll
    for (int i = 0; i < 2; ++i) {
      const int c = i * 8 + w;
      gload16(gB + (size_t)(c * 16) * F_ + t * 64 + kh * 32,
              lds + buf * 32768 + 16384 + kh * 8192 + c * 512);
    }
  };

  const u16* ldsA = lds + lane * 8;
  const u16* ldsB = lds + 16384 + lane * 8;

  f32x4 acc[8][4] = {};
  bf16x8 a[4], b[4];

  auto dsB = [&](int buf, int kh) {
#pragma unroll
    for (int ni = 0; ni < 4; ++ni)
      b[ni] =
          *(const bf16x8*)&ldsB[buf * 32768 + kh * 8192 + (wc * 4 + ni) * 512];
  };
  auto dsA = [&](int buf, int kh, int mh) {
#pragma unroll
    for (int mi = 0; mi < 4; ++mi)
      a[mi] = *(const bf16x8*)&ldsA[buf * 32768 + kh * 8192 +
                                    (wr * 8 + mh * 4 + mi) * 512];
  };
  auto mm = [&](int mh) {
    __builtin_amdgcn_s_setprio(1);
#pragma unroll
    for (int mi = 0; mi < 4; ++mi)
#pragma unroll
      for (int ni = 0; ni < 4; ++ni) mfma_b(acc[mh * 4 + mi][ni], a[mi], b[ni]);
    __builtin_amdgcn_s_setprio(0);
  };

  stB(0, 0, 0); stA(0, 0, 0); stB(0, 1, 0); stA(0, 1, 0);
  stB(1, 0, 1); stA(1, 0, 1); stB(1, 1, 1);
  WAITV(6);
  BARF;

  const int NT = F_ / 64;  // 64
  for (int t = 0; t <= NT - 4; t += 2) {
    dsB(0, 0); dsA(0, 0, 0); stA(t + 1, 1, 1);           BARF; mm(0); BARF;
    dsA(0, 0, 1);            stB(t + 2, 0, 0);           BARF; mm(1); BARF;
    dsB(0, 1); dsA(0, 1, 0); stA(t + 2, 0, 0);           BARF; mm(0); BARF;
    dsA(0, 1, 1);            stB(t + 2, 1, 0); WAITV(6); BARF; mm(1); BARF;
    dsB(1, 0); dsA(1, 0, 0); stA(t + 2, 1, 0);           BARF; mm(0); BARF;
    dsA(1, 0, 1);            stB(t + 3, 0, 1);           BARF; mm(1); BARF;
    dsB(1, 1); dsA(1, 1, 0); stA(t + 3, 0, 1);           BARF; mm(0); BARF;
    dsA(1, 1, 1);            stB(t + 3, 1, 1); WAITV(6); BARF; mm(1); BARF;
  }
  dsB(0, 0); dsA(0, 0, 0); stA(NT - 1, 1, 1); BARF; mm(0); BARF;
  dsA(0, 0, 1);                               BARF; mm(1); BARF;
  dsB(0, 1); dsA(0, 1, 0);                    BARF; mm(0); BARF;
  dsA(0, 1, 1);            WAITV(0);          BARF; mm(1); BARF;
  dsB(1, 0); dsA(1, 0, 0);                    BARF; mm(0); BARF;
  dsA(1, 0, 1);                               BARF; mm(1); BARF;
  dsB(1, 1); dsA(1, 1, 0);                    BARF; mm(0); BARF;
  dsA(1, 1, 1);                               BARF; mm(1);

  const int row0 = by * 256 + wr * 128 + g4 * 4;
  const int col0 = bx * 256 + wc * 64 + r15;
#pragma unroll
  for (int mI = 0; mI < 8; ++mI)
#pragma unroll
    for (int ni = 0; ni < 4; ++ni)
#pragma unroll
      for (int j = 0; j < 4; ++j)
        Out[(size_t)(row0 + mI * 16 + j) * H_ + col0 + ni * 16] =
            acc[mI][ni][j];
}

// ---------- host ----------

extern "C" void kernel_launch(void* const* d_in, const int* in_sizes, int n_in,
                              void* d_out, int out_size, void* d_ws,
                              size_t ws_size, hipStream_t stream) {
  (void)in_sizes;
  (void)n_in;
  (void)out_size;
  const float* x = (const float*)d_in[0];
  const float* wgu = (const float*)d_in[1];
  const float* wdn = (const float*)d_in[2];
  float* out = (float*)d_out;
  u16* ws = (u16*)d_ws;

  const size_t xbN = (size_t)T_ * H_;
  const size_t wguN = (size_t)E_ * 2 * F_ * H_;
  const size_t wdnN = (size_t)E_ * H_ * F_;
  const size_t hidN = (size_t)T_ * F_;
  const size_t fullBytes = (xbN + wguN + wdnN + hidN) * 2;  // 576 MiB

  dim3 cblk(256), gblk(512);

  if (ws_size >= fullBytes) {
    u16* xb = ws;
    u16* wgub = xb + xbN;
    u16* wdnb = wgub + wguN;
    u16* hid = wdnb + wdnN;
    cvt_kernel<<<2048, cblk, 0, stream>>>(x, xb, (long)(xbN / 4));
    cvt_kernel<<<4096, cblk, 0, stream>>>(wgu, wgub, (long)(wguN / 4));
    cvt_kernel<<<4096, cblk, 0, stream>>>(wdn, wdnb, (long)(wdnN / 4));
    gemm1_silu<<<dim3(F_ / 128, TE_ / 256, E_), gblk, 0, stream>>>(xb, wgub,
                                                                   hid);
    gemm2_down<<<dim3(H_ / 256, TE_ / 256, E_), gblk, 0, stream>>>(hid, wdnb,
                                                                   out);
  } else {
    u16* xb = ws;
    u16* wgub = xb + (size_t)TE_ * H_;
    u16* wdnb = wgub + (size_t)2 * F_ * H_;
    u16* hid = wdnb + (size_t)H_ * F_;
    for (int e = 0; e < E_; ++e) {
      cvt_kernel<<<1024, cblk, 0, stream>>>(x + (size_t)e * TE_ * H_, xb,
                                            (long)((size_t)TE_ * H_ / 4));
      cvt_kernel<<<2048, cblk, 0, stream>>>(wgu + (size_t)e * 2 * F_ * H_, wgub,
                                            (long)((size_t)2 * F_ * H_ / 4));
      cvt_kernel<<<2048, cblk, 0, stream>>>(wdn + (size_t)e * H_ * F_, wdnb,
                                            (long)((size_t)H_ * F_ / 4));
      gemm1_silu<<<dim3(F_ / 128, TE_ / 256, 1), gblk, 0, stream>>>(xb, wgub,
                                                                    hid);
      gemm2_down<<<dim3(H_ / 256, TE_ / 256, 1), gblk, 0, stream>>>(
          hid, wdnb, out + (size_t)e * TE_ * H_);
    }
  }
}